// Round 5
// baseline (1800.739 us; speedup 1.0000x reference)
//
#include <hip/hip_runtime.h>

// Problem constants (from reference): z [16,64,4096] f32, codebooks [8,1024,64] f32
#define S      8        // number of codebooks (stages)
#define K      1024     // codewords per codebook
#define D      64       // code dim
#define NVEC   65536    // B*T = 16*4096
#define VPB    64       // vectors per block (= lanes per wave)
#define NBLK   (NVEC / VPB)   // 1024 blocks
#define KPW    (K / 4)        // 256 codewords per wave (4 waves/block)
#define NELEM  4194304.0f     // B*T*D
#define EPSQ   1e-10f

// ---------------------------------------------------------------------------
// Prep: c2[s*K+k] = ||codebook[s][k]||^2 ; zero loss accumulators + histogram
// ---------------------------------------------------------------------------
__global__ void rvq_prep(const float* __restrict__ cb, float* __restrict__ c2,
                         float* __restrict__ loss_ws, unsigned* __restrict__ cnt) {
    int i = blockIdx.x * blockDim.x + threadIdx.x;  // 0..8191
    if (i < S * K) {
        const float* row = cb + i * D;
        float s0 = 0.f, s1 = 0.f, s2 = 0.f, s3 = 0.f;
#pragma unroll
        for (int d = 0; d < D; d += 4) {
            s0 = fmaf(row[d + 0], row[d + 0], s0);
            s1 = fmaf(row[d + 1], row[d + 1], s1);
            s2 = fmaf(row[d + 2], row[d + 2], s2);
            s3 = fmaf(row[d + 3], row[d + 3], s3);
        }
        c2[i] = (s0 + s1) + (s2 + s3);
        cnt[i] = 0u;
        if (i < S) loss_ws[i] = 0.0f;
    }
}

// ---------------------------------------------------------------------------
// Main: one lane per vector; 4 waves/block each scan a disjoint k-quarter.
// Codeword addresses forced wave-uniform via readfirstlane -> s_load.
// R4 lesson: under __launch_bounds__(256,4) (128-VGPR cap) the allocator
// spills r[64] once per stage (~112 MB of scratch traffic) regardless of
// load-burst shaping. (256,2) lifts the cap to 256 VGPRs so r[] stays
// resident; occupancy 2 blocks/CU is enough for this ILP-rich VALU loop.
// ---------------------------------------------------------------------------
__global__ __launch_bounds__(256, 2)
void rvq_main(const float* __restrict__ z, const float* __restrict__ cb,
              const float* __restrict__ c2, float* __restrict__ zq,
              float* __restrict__ loss_ws, unsigned* __restrict__ cnt) {
    __shared__ float lds_d[S][4][VPB];
    __shared__ int   lds_k[S][4][VPB];

    const int lane = threadIdx.x & 63;
    const int wave = threadIdx.x >> 6;
    const int vec  = blockIdx.x * VPB + lane;       // 64 consecutive t within one b
    const int b    = vec >> 12;                     // vec / 4096
    const int t    = vec & 4095;

    // Force wave-uniform k-range into SGPRs so codeword loads scalarize.
    const int kbeg = __builtin_amdgcn_readfirstlane(wave * KPW);

    const float* zbase = z + (((size_t)(b * D)) << 12) + t;  // z[b][d][t] = zbase[d<<12]

    float r[D];
#pragma unroll
    for (int d = 0; d < D; ++d) r[d] = zbase[((size_t)d) << 12];

    for (int s = 0; s < S; ++s) {
        const float* cbs = cb + s * (K * D);
        // wave-uniform bases (kbeg is SGPR, s is uniform)
        const float* cw0 = cbs + (size_t)kbeg * D;
        const float* c20 = c2 + s * K + kbeg;

        // --- argmin over this wave's k-quarter (scalar codeword loads) ---
        float bestd = 3.4e38f;
        int   bestk = 0;
        for (int kk = 0; kk < KPW; ++kk) {
            const float* cw = cw0 + kk * D;   // uniform -> s_load_dwordx16
            float a0 = 0.f, a1 = 0.f, a2 = 0.f, a3 = 0.f;
#pragma unroll
            for (int d = 0; d < D; d += 4) {
                a0 = fmaf(r[d + 0], cw[d + 0], a0);
                a1 = fmaf(r[d + 1], cw[d + 1], a1);
                a2 = fmaf(r[d + 2], cw[d + 2], a2);
                a3 = fmaf(r[d + 3], cw[d + 3], a3);
            }
            float score = c20[kk] - 2.0f * ((a0 + a1) + (a2 + a3));
            // branchless, strict < : first (lowest k) minimum wins ties
            bestk = (score < bestd) ? (kbeg + kk) : bestk;
            bestd = fminf(score, bestd);
        }

        // --- cross-wave argmin (per-stage LDS slot -> single barrier/stage) ---
        lds_d[s][wave][lane] = bestd;
        lds_k[s][wave][lane] = bestk;
        __syncthreads();
        float bd = lds_d[s][0][lane];
        int   bk = lds_k[s][0][lane];
#pragma unroll
        for (int w = 1; w < 4; ++w) {
            float dd = lds_d[s][w][lane];
            int   kk = lds_k[s][w][lane];
            bk = (dd < bd) ? kk : bk;   // lower wave = lower k wins ties
            bd = fminf(dd, bd);
        }

        // --- residual update: per-lane gather of the chosen codeword ---
        const float* qw = cbs + (size_t)bk * D;
#pragma unroll
        for (int c = 0; c < D; c += 16) {
            float4 q0 = *reinterpret_cast<const float4*>(qw + c + 0);
            float4 q1 = *reinterpret_cast<const float4*>(qw + c + 4);
            float4 q2 = *reinterpret_cast<const float4*>(qw + c + 8);
            float4 q3 = *reinterpret_cast<const float4*>(qw + c + 12);
            r[c +  0] -= q0.x; r[c +  1] -= q0.y; r[c +  2] -= q0.z; r[c +  3] -= q0.w;
            r[c +  4] -= q1.x; r[c +  5] -= q1.y; r[c +  6] -= q1.z; r[c +  7] -= q1.w;
            r[c +  8] -= q2.x; r[c +  9] -= q2.y; r[c + 10] -= q2.z; r[c + 11] -= q2.w;
            r[c + 12] -= q3.x; r[c + 13] -= q3.y; r[c + 14] -= q3.z; r[c + 15] -= q3.w;
        }

        // --- loss + histogram (wave 0 only; all waves hold identical r) ---
        if (wave == 0) {
            float ls = 0.f;
#pragma unroll
            for (int d = 0; d < D; ++d) ls = fmaf(r[d], r[d], ls);
#pragma unroll
            for (int off = 32; off > 0; off >>= 1) ls += __shfl_down(ls, off);
            if (lane == 0) atomicAdd(&loss_ws[s], ls);
            atomicAdd(&cnt[s * K + bk], 1u);
        }
    }

    // --- epilogue: zq = z - r_final (coalesced over t) ---
    if (wave == 0) {
        float* zqbase = zq + (((size_t)(b * D)) << 12) + t;
#pragma unroll
        for (int c = 0; c < D; c += 8) {
            float z0 = zbase[((size_t)(c + 0)) << 12];
            float z1 = zbase[((size_t)(c + 1)) << 12];
            float z2 = zbase[((size_t)(c + 2)) << 12];
            float z3 = zbase[((size_t)(c + 3)) << 12];
            float z4 = zbase[((size_t)(c + 4)) << 12];
            float z5 = zbase[((size_t)(c + 5)) << 12];
            float z6 = zbase[((size_t)(c + 6)) << 12];
            float z7 = zbase[((size_t)(c + 7)) << 12];
            zqbase[((size_t)(c + 0)) << 12] = z0 - r[c + 0];
            zqbase[((size_t)(c + 1)) << 12] = z1 - r[c + 1];
            zqbase[((size_t)(c + 2)) << 12] = z2 - r[c + 2];
            zqbase[((size_t)(c + 3)) << 12] = z3 - r[c + 3];
            zqbase[((size_t)(c + 4)) << 12] = z4 - r[c + 4];
            zqbase[((size_t)(c + 5)) << 12] = z5 - r[c + 5];
            zqbase[((size_t)(c + 6)) << 12] = z6 - r[c + 6];
            zqbase[((size_t)(c + 7)) << 12] = z7 - r[c + 7];
        }
    }
}

// ---------------------------------------------------------------------------
// Finalize: losses (mean) + perplexities (exp(-sum p ln(p+eps)))
// ---------------------------------------------------------------------------
__global__ void rvq_finalize(const float* __restrict__ loss_ws,
                             const unsigned* __restrict__ cnt,
                             float* __restrict__ out_loss,
                             float* __restrict__ out_perp) {
    const int s   = blockIdx.x;     // 8 blocks
    const int tid = threadIdx.x;    // 256 threads
    float partial = 0.f;
    for (int i = tid; i < K; i += 256) {
        float p = (float)cnt[s * K + i] * (1.0f / 65536.0f);
        partial += p * logf(p + EPSQ);
    }
    __shared__ float red[4];
#pragma unroll
    for (int off = 32; off > 0; off >>= 1) partial += __shfl_down(partial, off);
    if ((tid & 63) == 0) red[tid >> 6] = partial;
    __syncthreads();
    if (tid == 0) {
        float tot = red[0] + red[1] + red[2] + red[3];
        out_perp[s] = expf(-tot);
        out_loss[s] = loss_ws[s] * (1.0f / NELEM);
    }
}

// ---------------------------------------------------------------------------
extern "C" void kernel_launch(void* const* d_in, const int* in_sizes, int n_in,
                              void* d_out, int out_size, void* d_ws, size_t ws_size,
                              hipStream_t stream) {
    const float* z  = (const float*)d_in[0];   // [16,64,4096]
    const float* cb = (const float*)d_in[1];   // [8,1024,64]

    float* zq       = (float*)d_out;           // 4194304
    float* out_loss = zq + 4194304;            // 8
    float* out_perp = out_loss + 8;            // 8

    float*    c2      = (float*)d_ws;          // 8192 floats
    float*    loss_ws = c2 + S * K;            // 8 floats
    unsigned* cnt     = (unsigned*)(loss_ws + S); // 8192 uints

    hipLaunchKernelGGL(rvq_prep,     dim3(32),   dim3(256), 0, stream, cb, c2, loss_ws, cnt);
    hipLaunchKernelGGL(rvq_main,     dim3(NBLK), dim3(256), 0, stream, z, cb, c2, zq, loss_ws, cnt);
    hipLaunchKernelGGL(rvq_finalize, dim3(S),    dim3(256), 0, stream, loss_ws, cnt, out_loss, out_perp);
}

// Round 6
// 777.881 us; speedup vs baseline: 2.3149x; 2.3149x over previous
//
#include <hip/hip_runtime.h>

// RVQ: z [16,64,4096] f32, codebooks [8,1024,64] f32 -> zq + 8 losses + 8 perplexities
#define S      8
#define K      1024
#define D      64
#define NVEC   65536
#define NELEM  4194304.0f
#define EPSQ   1e-10f
#define DELTA  0.02f     // rescue margin >> split-bf16 score error bound (~1.6e-3)

typedef __attribute__((ext_vector_type(8))) short  short8;   // 8 bf16 (4 VGPRs)
typedef __attribute__((ext_vector_type(4))) float  float4v;  // MFMA acc

// bf16 round-to-nearest-even (manual; avoids __hip_bfloat16 ABI surprises)
static __device__ inline unsigned short f2bf(float f) {
    unsigned int u = __float_as_uint(f);
    u = (u + 0x7FFFu + ((u >> 16) & 1u)) >> 16;
    return (unsigned short)u;
}
static __device__ inline float bf2f(unsigned short h) {
    return __uint_as_float(((unsigned int)h) << 16);
}

// ---------------------------------------------------------------------------
// Prep: split codebook into swizzled bf16 hi/lo arrays + c2 + zero accums.
// Swizzle: 16-B group g of row n stored at slot (g ^ (n&7)) -> conflict-free
// ds_read_b128 B-fragment reads in the main kernel.
// ---------------------------------------------------------------------------
__global__ void rvq_prep(const float* __restrict__ cb,
                         unsigned short* __restrict__ cbh,
                         unsigned short* __restrict__ cbl,
                         float* __restrict__ c2, float* __restrict__ loss_ws,
                         unsigned* __restrict__ cnt) {
    int i = blockIdx.x * blockDim.x + threadIdx.x;   // 0..8191  (= s*K + n)
    if (i >= S * K) return;
    const float* row = cb + (size_t)i * D;
    unsigned short hb[D], lb[D];
    float acc = 0.f;
#pragma unroll
    for (int d = 0; d < D; ++d) {
        float x = row[d];
        acc = fmaf(x, x, acc);
        unsigned short h = f2bf(x);
        hb[d] = h;
        lb[d] = f2bf(x - bf2f(h));
    }
    c2[i] = acc;
    cnt[i] = 0u;
    if (i < S) loss_ws[i] = 0.0f;
    int n7 = i & 7;
#pragma unroll
    for (int g = 0; g < 8; ++g) {
        int slot = g ^ n7;
        short8 vh, vl;
#pragma unroll
        for (int e = 0; e < 8; ++e) { vh[e] = (short)hb[g*8+e]; vl[e] = (short)lb[g*8+e]; }
        *(short8*)(cbh + (size_t)i*64 + slot*8) = vh;
        *(short8*)(cbl + (size_t)i*64 + slot*8) = vl;
    }
}

// ---------------------------------------------------------------------------
// Main: block = 4 waves x 16 vectors. Per stage: scores = c2 - 2*X*C^T via
// split-bf16 MFMA (3 terms), codebook chunks (128 cw, 32 KB) staged in LDS
// via global_load_lds. Top-2 tracking + exact fp32 rescan when gap < DELTA.
// Residual/loss/zq all pure fp32 — bf16 affects selection only.
// ---------------------------------------------------------------------------
__global__ __launch_bounds__(256, 3)
void rvq_main(const float* __restrict__ z, const float* __restrict__ cbf,
              const unsigned short* __restrict__ cbh,
              const unsigned short* __restrict__ cbl,
              const float* __restrict__ c2, float* __restrict__ zq,
              float* __restrict__ loss_ws, unsigned* __restrict__ cnt) {
    __shared__ __align__(16) unsigned short lds_h[8192];  // 16 KB: 128 rows x 64
    __shared__ __align__(16) unsigned short lds_l[8192];  // 16 KB

    const int tid  = threadIdx.x;
    const int lane = tid & 63;
    const int wave = tid >> 6;
    const int m    = lane & 15;   // A-row / B-col / C-col index
    const int q    = lane >> 4;   // quad
    const int vec  = blockIdx.x * 64 + wave * 16 + m;
    const int b    = vec >> 12;
    const int t    = vec & 4095;

    const size_t zrow = ((size_t)(b * 64)) << 12;   // z[b][d][t] = z[zrow + (d<<12) + t]

    // fp32 residual in A-fragment layout: lane (m,q) holds dims q*8+i and 32+q*8+i
    float r0[8], r1[8];
#pragma unroll
    for (int i = 0; i < 8; ++i) r0[i] = z[zrow + ((size_t)(q*8+i)    << 12) + t];
#pragma unroll
    for (int i = 0; i < 8; ++i) r1[i] = z[zrow + ((size_t)(32+q*8+i) << 12) + t];

    // lane-invariant LDS B-frag offsets: slot(ks) = (ks*4+q) ^ (m&7), row m*128 B
    const int slot0  = ((q)     ^ (lane & 7)) * 16;
    const int slot1  = ((4 + q) ^ (lane & 7)) * 16;
    const int rowoff = m * 128;

#pragma unroll 1
    for (int s = 0; s < S; ++s) {
        // ---- split residual to bf16 hi/lo A-fragments ----
        short8 xh0, xh1, xl0, xl1;
#pragma unroll
        for (int i = 0; i < 8; ++i) {
            unsigned short h = f2bf(r0[i]);
            xh0[i] = (short)h; xl0[i] = (short)f2bf(r0[i] - bf2f(h));
            unsigned short g = f2bf(r1[i]);
            xh1[i] = (short)g; xl1[i] = (short)f2bf(r1[i] - bf2f(g));
        }

        float b1v[4] = {3.4e38f, 3.4e38f, 3.4e38f, 3.4e38f};
        float b2v[4] = {3.4e38f, 3.4e38f, 3.4e38f, 3.4e38f};
        int   k1v[4] = {0, 0, 0, 0};

        const unsigned short* gh  = cbh + (size_t)s * 65536;
        const unsigned short* gl  = cbl + (size_t)s * 65536;
        const float*          c2s = c2 + s * K;

#pragma unroll 1
        for (int c = 0; c < 8; ++c) {
            __syncthreads();   // previous chunk's readers done
            {
                const char* sh = (const char*)(gh + (size_t)c * 8192);
                const char* sl = (const char*)(gl + (size_t)c * 8192);
#pragma unroll
                for (int rr = 0; rr < 4; ++rr) {
                    int off = rr * 4096 + tid * 16;
                    __builtin_amdgcn_global_load_lds(
                        (const __attribute__((address_space(1))) unsigned int*)(sh + off),
                        (__attribute__((address_space(3))) unsigned int*)((char*)lds_h + off),
                        16, 0, 0);
                    __builtin_amdgcn_global_load_lds(
                        (const __attribute__((address_space(1))) unsigned int*)(sl + off),
                        (__attribute__((address_space(3))) unsigned int*)((char*)lds_l + off),
                        16, 0, 0);
                }
            }
            __syncthreads();   // staged -> visible (drains vmcnt)

#pragma unroll
            for (int tl = 0; tl < 8; ++tl) {
                int ncol = c * 128 + tl * 16 + m;
                float c2v = c2s[ncol];
                const char* bh = (const char*)lds_h + tl * 2048 + rowoff;
                const char* bl = (const char*)lds_l + tl * 2048 + rowoff;
                short8 ch0 = *(const short8*)(bh + slot0);
                short8 ch1 = *(const short8*)(bh + slot1);
                short8 cl0 = *(const short8*)(bl + slot0);
                short8 cl1 = *(const short8*)(bl + slot1);
                float4v acc = {0.f, 0.f, 0.f, 0.f};
                acc = __builtin_amdgcn_mfma_f32_16x16x32_bf16(xh0, ch0, acc, 0, 0, 0);
                acc = __builtin_amdgcn_mfma_f32_16x16x32_bf16(xl0, ch0, acc, 0, 0, 0);
                acc = __builtin_amdgcn_mfma_f32_16x16x32_bf16(xh0, cl0, acc, 0, 0, 0);
                acc = __builtin_amdgcn_mfma_f32_16x16x32_bf16(xh1, ch1, acc, 0, 0, 0);
                acc = __builtin_amdgcn_mfma_f32_16x16x32_bf16(xl1, ch1, acc, 0, 0, 0);
                acc = __builtin_amdgcn_mfma_f32_16x16x32_bf16(xh1, cl1, acc, 0, 0, 0);
#pragma unroll
                for (int j = 0; j < 4; ++j) {           // row = q*4+j, col = ncol
                    float sc = fmaf(-2.f, acc[j], c2v);
                    b2v[j] = fminf(b2v[j], fmaxf(sc, b1v[j]));
                    k1v[j] = (sc < b1v[j]) ? ncol : k1v[j];   // strict <, ascending n
                    b1v[j] = fminf(sc, b1v[j]);
                }
            }
        }

        // ---- reduce across the 16 col-lanes (k-tie: lowest k) ----
#pragma unroll
        for (int off = 1; off < 16; off <<= 1) {
#pragma unroll
            for (int j = 0; j < 4; ++j) {
                float ob1 = __shfl_xor(b1v[j], off);
                int   ok1 = __shfl_xor(k1v[j], off);
                float ob2 = __shfl_xor(b2v[j], off);
                float nb2 = fminf(fminf(b2v[j], ob2), fmaxf(b1v[j], ob1));
                bool take = (ob1 < b1v[j]) || (ob1 == b1v[j] && ok1 < k1v[j]);
                k1v[j] = take ? ok1 : k1v[j];
                b1v[j] = fminf(b1v[j], ob1);
                b2v[j] = nb2;
            }
        }

        // ---- δ-rescue: exact fp32 rescan of ambiguous rows (rare) ----
#pragma unroll 1
        for (int j = 0; j < 4; ++j) {
            unsigned long long mask = __ballot(b2v[j] - b1v[j] < DELTA);
            while (mask) {
                int lq = (int)(__builtin_ctzll(mask)) >> 4;   // flagged quad
                mask &= ~(0xFFFFULL << (lq * 16));
                int mrow = lq * 4 + j;                        // wave-uniform row
                float bd = 3.4e38f; int bk = 0;
                const float* cr0 = cbf + (size_t)s * 65536;
#pragma unroll 1
                for (int cc = 0; cc < 16; ++cc) {
                    int n = cc * 64 + lane;
                    const float* crow = cr0 + (size_t)n * 64;
                    float dot = 0.f;
#pragma unroll
                    for (int p = 0; p < 4; ++p) {
#pragma unroll
                        for (int i = 0; i < 8; ++i)
                            dot = fmaf(__shfl(r0[i], mrow + 16*p), crow[p*8+i], dot);
#pragma unroll
                        for (int i = 0; i < 8; ++i)
                            dot = fmaf(__shfl(r1[i], mrow + 16*p), crow[32+p*8+i], dot);
                    }
                    float sc = c2s[n] - 2.f * dot;
                    if (sc < bd) { bd = sc; bk = n; }         // ascending n per lane
                }
#pragma unroll
                for (int off = 1; off < 64; off <<= 1) {      // merge, k-tie
                    float ob = __shfl_xor(bd, off);
                    int   ok = __shfl_xor(bk, off);
                    bool take = (ob < bd) || (ob == bd && ok < bk);
                    bk = take ? ok : bk;
                    bd = fminf(bd, ob);
                }
                if (q == lq) k1v[j] = bk;
            }
        }

        // ---- transpose winners to A-layout: bk for row m = lane&15 ----
        int w0 = __shfl(k1v[0], (m >> 2) * 16);
        int w1 = __shfl(k1v[1], (m >> 2) * 16);
        int w2 = __shfl(k1v[2], (m >> 2) * 16);
        int w3 = __shfl(k1v[3], (m >> 2) * 16);
        int mm = m & 3;
        int bkm = (mm == 0) ? w0 : (mm == 1) ? w1 : (mm == 2) ? w2 : w3;

        // ---- fp32 residual update ----
        const float* qrow = cbf + (size_t)s * 65536 + (size_t)bkm * 64;
#pragma unroll
        for (int i = 0; i < 8; ++i) r0[i] -= qrow[q*8+i];
#pragma unroll
        for (int i = 0; i < 8; ++i) r1[i] -= qrow[32+q*8+i];

        // ---- loss (sum of r_next^2 over the wave's 16 vectors) ----
        float ls = 0.f;
#pragma unroll
        for (int i = 0; i < 8; ++i) { ls = fmaf(r0[i], r0[i], ls); ls = fmaf(r1[i], r1[i], ls); }
#pragma unroll
        for (int off = 1; off < 64; off <<= 1) ls += __shfl_xor(ls, off);
        if (lane == 0) atomicAdd(&loss_ws[s], ls);

        // ---- histogram: one count per row (q==0 lanes) ----
        if (lane < 16) atomicAdd(&cnt[s * K + bkm], 1u);
    }

    // ---- epilogue: zq = z - r_final ----
#pragma unroll
    for (int i = 0; i < 8; ++i) {
        size_t a = zrow + ((size_t)(q*8+i) << 12) + t;
        zq[a] = z[a] - r0[i];
    }
#pragma unroll
    for (int i = 0; i < 8; ++i) {
        size_t a = zrow + ((size_t)(32+q*8+i) << 12) + t;
        zq[a] = z[a] - r1[i];
    }
}

// ---------------------------------------------------------------------------
// Finalize: losses (mean) + perplexities
// ---------------------------------------------------------------------------
__global__ void rvq_finalize(const float* __restrict__ loss_ws,
                             const unsigned* __restrict__ cnt,
                             float* __restrict__ out_loss,
                             float* __restrict__ out_perp) {
    const int s   = blockIdx.x;
    const int tid = threadIdx.x;
    float partial = 0.f;
    for (int i = tid; i < K; i += 256) {
        float p = (float)cnt[s * K + i] * (1.0f / 65536.0f);
        partial += p * logf(p + EPSQ);
    }
    __shared__ float red[4];
#pragma unroll
    for (int off = 32; off > 0; off >>= 1) partial += __shfl_down(partial, off);
    if ((tid & 63) == 0) red[tid >> 6] = partial;
    __syncthreads();
    if (tid == 0) {
        float tot = red[0] + red[1] + red[2] + red[3];
        out_perp[s] = expf(-tot);
        out_loss[s] = loss_ws[s] * (1.0f / NELEM);
    }
}

// ---------------------------------------------------------------------------
extern "C" void kernel_launch(void* const* d_in, const int* in_sizes, int n_in,
                              void* d_out, int out_size, void* d_ws, size_t ws_size,
                              hipStream_t stream) {
    const float* z  = (const float*)d_in[0];
    const float* cb = (const float*)d_in[1];

    float* zq       = (float*)d_out;
    float* out_loss = zq + 4194304;
    float* out_perp = out_loss + 8;

    // workspace: cbh 1 MB | cbl 1 MB | c2 32 KB | loss 32 B | cnt 32 KB
    char* ws = (char*)d_ws;
    unsigned short* cbh = (unsigned short*)(ws);
    unsigned short* cbl = (unsigned short*)(ws + 1048576);
    float*    c2        = (float*)(ws + 2097152);
    float*    loss_ws   = (float*)(ws + 2129920);
    unsigned* cnt       = (unsigned*)(ws + 2129984);

    hipLaunchKernelGGL(rvq_prep,     dim3(32),   dim3(256), 0, stream, cb, cbh, cbl, c2, loss_ws, cnt);
    hipLaunchKernelGGL(rvq_main,     dim3(1024), dim3(256), 0, stream, z, cb, cbh, cbl, c2, zq, loss_ws, cnt);
    hipLaunchKernelGGL(rvq_finalize, dim3(S),    dim3(256), 0, stream, loss_ws, cnt, out_loss, out_perp);
}

// Round 7
// 703.719 us; speedup vs baseline: 2.5589x; 1.1054x over previous
//
#include <hip/hip_runtime.h>

// RVQ: z [16,64,4096] f32, codebooks [8,1024,64] f32 -> zq + 8 losses + 8 perplexities
#define S      8
#define K      1024
#define D      64
#define NVEC   65536
#define NELEM  4194304.0f
#define EPSQ   1e-10f
// Rescue margin: split-bf16 score-error bound ~2e-4 (typ), ~2e-3 (adversarial
// tail on a score DIFFERENCE). 5e-3 keeps >2.5x margin; R6 ran 0.02 with zero
// selection flips but ~10x too many rescues (the 778us dominator).
#define DELTA  0.005f

typedef __attribute__((ext_vector_type(8))) short  short8;   // 8 bf16 (4 VGPRs)
typedef __attribute__((ext_vector_type(4))) float  float4v;  // MFMA acc

static __device__ inline unsigned short f2bf(float f) {
    unsigned int u = __float_as_uint(f);
    u = (u + 0x7FFFu + ((u >> 16) & 1u)) >> 16;
    return (unsigned short)u;
}
static __device__ inline float bf2f(unsigned short h) {
    return __uint_as_float(((unsigned int)h) << 16);
}

// ---------------------------------------------------------------------------
// Prep: split codebook into swizzled bf16 hi/lo arrays + c2 + zero accums.
// Swizzle: 16-B group g of row n stored at slot (g ^ (n&7)) -> conflict-free
// ds_read_b128 B-fragment reads in the main kernel.
// ---------------------------------------------------------------------------
__global__ void rvq_prep(const float* __restrict__ cb,
                         unsigned short* __restrict__ cbh,
                         unsigned short* __restrict__ cbl,
                         float* __restrict__ c2, float* __restrict__ loss_ws,
                         unsigned* __restrict__ cnt) {
    int i = blockIdx.x * blockDim.x + threadIdx.x;   // 0..8191  (= s*K + n)
    if (i >= S * K) return;
    const float* row = cb + (size_t)i * D;
    unsigned short hb[D], lb[D];
    float acc = 0.f;
#pragma unroll
    for (int d = 0; d < D; ++d) {
        float x = row[d];
        acc = fmaf(x, x, acc);
        unsigned short h = f2bf(x);
        hb[d] = h;
        lb[d] = f2bf(x - bf2f(h));
    }
    c2[i] = acc;
    cnt[i] = 0u;
    if (i < S) loss_ws[i] = 0.0f;
    int n7 = i & 7;
#pragma unroll
    for (int g = 0; g < 8; ++g) {
        int slot = g ^ n7;
        short8 vh, vl;
#pragma unroll
        for (int e = 0; e < 8; ++e) { vh[e] = (short)hb[g*8+e]; vl[e] = (short)lb[g*8+e]; }
        *(short8*)(cbh + (size_t)i*64 + slot*8) = vh;
        *(short8*)(cbl + (size_t)i*64 + slot*8) = vl;
    }
}

// ---------------------------------------------------------------------------
// Main: block = 4 waves x 16 vectors. Per stage: scores = c2 - 2*X*C^T via
// split-bf16 MFMA (3 terms/half). Codebook staged in LDS as 16 double-
// buffered chunks of 64 codewords (2 x 16 KB): stage chunk c+1 after the
// barrier while computing chunk c -> L2 drain hides under compute.
// Top-2 tracking + exact fp32 rescan when gap < DELTA (rare at 5e-3).
// Residual/loss/zq all pure fp32 — bf16 affects selection only.
// ---------------------------------------------------------------------------
__global__ __launch_bounds__(256, 3)
void rvq_main(const float* __restrict__ z, const float* __restrict__ cbf,
              const unsigned short* __restrict__ cbh,
              const unsigned short* __restrict__ cbl,
              const float* __restrict__ c2, float* __restrict__ zq,
              float* __restrict__ loss_ws, unsigned* __restrict__ cnt) {
    // [buf][0..4095]=hi chunk (64 rows x 64), [buf][4096..8191]=lo chunk
    __shared__ __align__(16) unsigned short lds_buf[2][8192];

    const int tid  = threadIdx.x;
    const int lane = tid & 63;
    const int wave = tid >> 6;
    const int m    = lane & 15;   // A-row / B-col / C-col index
    const int q    = lane >> 4;   // quad
    const int vec  = blockIdx.x * 64 + wave * 16 + m;
    const int b    = vec >> 12;
    const int t    = vec & 4095;

    const size_t zrow = ((size_t)(b * 64)) << 12;   // z[b][d][t] = z[zrow + (d<<12) + t]

    // fp32 residual in A-fragment layout: lane (m,q) holds dims q*8+i and 32+q*8+i
    float r0[8], r1[8];
#pragma unroll
    for (int i = 0; i < 8; ++i) r0[i] = z[zrow + ((size_t)(q*8+i)    << 12) + t];
#pragma unroll
    for (int i = 0; i < 8; ++i) r1[i] = z[zrow + ((size_t)(32+q*8+i) << 12) + t];

    // lane-invariant LDS B-frag offsets: slot(ks) = (ks*4+q) ^ (m&7), row m*128 B
    const int slot0  = ((q)     ^ (lane & 7)) * 16;
    const int slot1  = ((4 + q) ^ (lane & 7)) * 16;
    const int rowoff = m * 128;

#pragma unroll 1
    for (int s = 0; s < S; ++s) {
        // ---- split residual to bf16 hi/lo A-fragments ----
        short8 xh0, xh1, xl0, xl1;
#pragma unroll
        for (int i = 0; i < 8; ++i) {
            unsigned short h = f2bf(r0[i]);
            xh0[i] = (short)h; xl0[i] = (short)f2bf(r0[i] - bf2f(h));
            unsigned short g = f2bf(r1[i]);
            xh1[i] = (short)g; xl1[i] = (short)f2bf(r1[i] - bf2f(g));
        }

        float b1v[4] = {3.4e38f, 3.4e38f, 3.4e38f, 3.4e38f};
        float b2v[4] = {3.4e38f, 3.4e38f, 3.4e38f, 3.4e38f};
        int   k1v[4] = {0, 0, 0, 0};

        const unsigned short* gh  = cbh + (size_t)s * 65536;
        const unsigned short* gl  = cbl + (size_t)s * 65536;
        const float*          c2s = c2 + s * K;

        // ---- prologue: stage chunk 0 into buf 0 ----
        {
            const char* srch = (const char*)(gh);
            const char* srcl = (const char*)(gl);
            char*       dst  = (char*)&lds_buf[0][0];
#pragma unroll
            for (int rr = 0; rr < 2; ++rr) {
                int off = rr * 4096 + tid * 16;
                __builtin_amdgcn_global_load_lds(
                    (const __attribute__((address_space(1))) unsigned int*)(srch + off),
                    (__attribute__((address_space(3))) unsigned int*)(dst + off),
                    16, 0, 0);
                __builtin_amdgcn_global_load_lds(
                    (const __attribute__((address_space(1))) unsigned int*)(srcl + off),
                    (__attribute__((address_space(3))) unsigned int*)(dst + 8192 + off),
                    16, 0, 0);
            }
        }

#pragma unroll 1
        for (int c = 0; c < 16; ++c) {
            __syncthreads();   // chunk c staged+visible; buf[(c+1)&1] free
            if (c + 1 < 16) {  // stage next chunk while computing this one
                const char* srch = (const char*)(gh + (size_t)(c + 1) * 4096);
                const char* srcl = (const char*)(gl + (size_t)(c + 1) * 4096);
                char*       dst  = (char*)&lds_buf[(c + 1) & 1][0];
#pragma unroll
                for (int rr = 0; rr < 2; ++rr) {
                    int off = rr * 4096 + tid * 16;
                    __builtin_amdgcn_global_load_lds(
                        (const __attribute__((address_space(1))) unsigned int*)(srch + off),
                        (__attribute__((address_space(3))) unsigned int*)(dst + off),
                        16, 0, 0);
                    __builtin_amdgcn_global_load_lds(
                        (const __attribute__((address_space(1))) unsigned int*)(srcl + off),
                        (__attribute__((address_space(3))) unsigned int*)(dst + 8192 + off),
                        16, 0, 0);
                }
            }
            const char* bufb = (const char*)&lds_buf[c & 1][0];

#pragma unroll
            for (int tl = 0; tl < 4; ++tl) {
                int ncol = c * 64 + tl * 16 + m;
                float c2v = c2s[ncol];
                const char* bh = bufb + tl * 2048 + rowoff;
                const char* bl = bh + 8192;
                short8 ch0 = *(const short8*)(bh + slot0);
                short8 ch1 = *(const short8*)(bh + slot1);
                short8 cl0 = *(const short8*)(bl + slot0);
                short8 cl1 = *(const short8*)(bl + slot1);
                float4v acc = {0.f, 0.f, 0.f, 0.f};
                acc = __builtin_amdgcn_mfma_f32_16x16x32_bf16(xh0, ch0, acc, 0, 0, 0);
                acc = __builtin_amdgcn_mfma_f32_16x16x32_bf16(xl0, ch0, acc, 0, 0, 0);
                acc = __builtin_amdgcn_mfma_f32_16x16x32_bf16(xh0, cl0, acc, 0, 0, 0);
                acc = __builtin_amdgcn_mfma_f32_16x16x32_bf16(xh1, ch1, acc, 0, 0, 0);
                acc = __builtin_amdgcn_mfma_f32_16x16x32_bf16(xl1, ch1, acc, 0, 0, 0);
                acc = __builtin_amdgcn_mfma_f32_16x16x32_bf16(xh1, cl1, acc, 0, 0, 0);
#pragma unroll
                for (int j = 0; j < 4; ++j) {           // row = q*4+j, col = ncol
                    float sc = fmaf(-2.f, acc[j], c2v);
                    b2v[j] = fminf(b2v[j], fmaxf(sc, b1v[j]));
                    k1v[j] = (sc < b1v[j]) ? ncol : k1v[j];   // strict <, ascending n
                    b1v[j] = fminf(sc, b1v[j]);
                }
            }
        }

        // ---- reduce across the 16 col-lanes (k-tie: lowest k) ----
#pragma unroll
        for (int off = 1; off < 16; off <<= 1) {
#pragma unroll
            for (int j = 0; j < 4; ++j) {
                float ob1 = __shfl_xor(b1v[j], off);
                int   ok1 = __shfl_xor(k1v[j], off);
                float ob2 = __shfl_xor(b2v[j], off);
                float nb2 = fminf(fminf(b2v[j], ob2), fmaxf(b1v[j], ob1));
                bool take = (ob1 < b1v[j]) || (ob1 == b1v[j] && ok1 < k1v[j]);
                k1v[j] = take ? ok1 : k1v[j];
                b1v[j] = fminf(b1v[j], ob1);
                b2v[j] = nb2;
            }
        }

        // ---- δ-rescue: exact fp32 rescan of ambiguous rows (rare) ----
#pragma unroll 1
        for (int j = 0; j < 4; ++j) {
            unsigned long long mask = __ballot(b2v[j] - b1v[j] < DELTA);
            while (mask) {
                int lq = (int)(__builtin_ctzll(mask)) >> 4;   // flagged quad
                mask &= ~(0xFFFFULL << (lq * 16));
                int mrow = lq * 4 + j;                        // wave-uniform row
                float bd = 3.4e38f; int bk = 0;
                const float* cr0 = cbf + (size_t)s * 65536;
#pragma unroll 1
                for (int cc = 0; cc < 16; ++cc) {
                    int n = cc * 64 + lane;
                    const float* crow = cr0 + (size_t)n * 64;
                    float dot = 0.f;
#pragma unroll
                    for (int p = 0; p < 4; ++p) {
#pragma unroll
                        for (int i = 0; i < 8; ++i)
                            dot = fmaf(__shfl(r0[i], mrow + 16*p), crow[p*8+i], dot);
#pragma unroll
                        for (int i = 0; i < 8; ++i)
                            dot = fmaf(__shfl(r1[i], mrow + 16*p), crow[32+p*8+i], dot);
                    }
                    float sc = c2s[n] - 2.f * dot;
                    if (sc < bd) { bd = sc; bk = n; }         // ascending n per lane
                }
#pragma unroll
                for (int off = 1; off < 64; off <<= 1) {      // merge, k-tie
                    float ob = __shfl_xor(bd, off);
                    int   ok = __shfl_xor(bk, off);
                    bool take = (ob < bd) || (ob == bd && ok < bk);
                    bk = take ? ok : bk;
                    bd = fminf(bd, ob);
                }
                if (q == lq) k1v[j] = bk;
            }
        }

        // ---- transpose winners to A-layout: bk for row m = lane&15 ----
        int w0 = __shfl(k1v[0], (m >> 2) * 16);
        int w1 = __shfl(k1v[1], (m >> 2) * 16);
        int w2 = __shfl(k1v[2], (m >> 2) * 16);
        int w3 = __shfl(k1v[3], (m >> 2) * 16);
        int mm = m & 3;
        int bkm = (mm == 0) ? w0 : (mm == 1) ? w1 : (mm == 2) ? w2 : w3;

        // ---- fp32 residual update ----
        const float* qrow = cbf + (size_t)s * 65536 + (size_t)bkm * 64;
#pragma unroll
        for (int i = 0; i < 8; ++i) r0[i] -= qrow[q*8+i];
#pragma unroll
        for (int i = 0; i < 8; ++i) r1[i] -= qrow[32+q*8+i];

        // ---- loss (sum of r_next^2 over the wave's 16 vectors) ----
        float ls = 0.f;
#pragma unroll
        for (int i = 0; i < 8; ++i) { ls = fmaf(r0[i], r0[i], ls); ls = fmaf(r1[i], r1[i], ls); }
#pragma unroll
        for (int off = 1; off < 64; off <<= 1) ls += __shfl_xor(ls, off);
        if (lane == 0) atomicAdd(&loss_ws[s], ls);

        // ---- histogram: one count per row (q==0 lanes) ----
        if (lane < 16) atomicAdd(&cnt[s * K + bkm], 1u);
    }

    // ---- epilogue: zq = z - r_final ----
#pragma unroll
    for (int i = 0; i < 8; ++i) {
        size_t a = zrow + ((size_t)(q*8+i) << 12) + t;
        zq[a] = z[a] - r0[i];
    }
#pragma unroll
    for (int i = 0; i < 8; ++i) {
        size_t a = zrow + ((size_t)(32+q*8+i) << 12) + t;
        zq[a] = z[a] - r1[i];
    }
}

// ---------------------------------------------------------------------------
// Finalize: losses (mean) + perplexities
// ---------------------------------------------------------------------------
__global__ void rvq_finalize(const float* __restrict__ loss_ws,
                             const unsigned* __restrict__ cnt,
                             float* __restrict__ out_loss,
                             float* __restrict__ out_perp) {
    const int s   = blockIdx.x;
    const int tid = threadIdx.x;
    float partial = 0.f;
    for (int i = tid; i < K; i += 256) {
        float p = (float)cnt[s * K + i] * (1.0f / 65536.0f);
        partial += p * logf(p + EPSQ);
    }
    __shared__ float red[4];
#pragma unroll
    for (int off = 32; off > 0; off >>= 1) partial += __shfl_down(partial, off);
    if ((tid & 63) == 0) red[tid >> 6] = partial;
    __syncthreads();
    if (tid == 0) {
        float tot = red[0] + red[1] + red[2] + red[3];
        out_perp[s] = expf(-tot);
        out_loss[s] = loss_ws[s] * (1.0f / NELEM);
    }
}

// ---------------------------------------------------------------------------
extern "C" void kernel_launch(void* const* d_in, const int* in_sizes, int n_in,
                              void* d_out, int out_size, void* d_ws, size_t ws_size,
                              hipStream_t stream) {
    const float* z  = (const float*)d_in[0];
    const float* cb = (const float*)d_in[1];

    float* zq       = (float*)d_out;
    float* out_loss = zq + 4194304;
    float* out_perp = out_loss + 8;

    // workspace: cbh 1 MB | cbl 1 MB | c2 32 KB | loss 32 B | cnt 32 KB
    char* ws = (char*)d_ws;
    unsigned short* cbh = (unsigned short*)(ws);
    unsigned short* cbl = (unsigned short*)(ws + 1048576);
    float*    c2        = (float*)(ws + 2097152);
    float*    loss_ws   = (float*)(ws + 2129920);
    unsigned* cnt       = (unsigned*)(ws + 2129984);

    hipLaunchKernelGGL(rvq_prep,     dim3(32),   dim3(256), 0, stream, cb, cbh, cbl, c2, loss_ws, cnt);
    hipLaunchKernelGGL(rvq_main,     dim3(1024), dim3(256), 0, stream, z, cb, cbh, cbl, c2, zq, loss_ws, cnt);
    hipLaunchKernelGGL(rvq_finalize, dim3(S),    dim3(256), 0, stream, loss_ws, cnt, out_loss, out_perp);
}

// Round 9
// 454.665 us; speedup vs baseline: 3.9606x; 1.5478x over previous
//
#include <hip/hip_runtime.h>

// RVQ: z [16,64,4096] f32, codebooks [8,1024,64] f32 -> zq + 8 losses + 8 perplexities
#define S      8
#define K      1024
#define D      64
#define NVEC   65536
#define NW     2048      // single-wave blocks, 32 vectors each
#define NELEM  4194304.0f
#define EPSQ   1e-10f
#define DELTA  0.005f    // exact-rescan margin >> split-bf16 score error (~2e-3 worst)

typedef __attribute__((ext_vector_type(8))) short  short8;   // 8 bf16
typedef __attribute__((ext_vector_type(4))) float  float4v;  // MFMA acc

static __device__ inline unsigned short f2bf(float f) {
    unsigned int u = __float_as_uint(f);
    u = (u + 0x7FFFu + ((u >> 16) & 1u)) >> 16;
    return (unsigned short)u;
}
static __device__ inline float bf2f(unsigned short h) {
    return __uint_as_float(((unsigned int)h) << 16);
}

// ---------------------------------------------------------------------------
// Prep: (a) c2 + zero cnt; (b) interleave codebook into B-fragment streaming
// records: per (stage, tile of 16 cw) a 4 KB record of 4 segments
// [h0hi][h1hi][h0lo][h1lo]; slot l holds cw=tile*16+(l&15),
// dims h*32+(l>>4)*8+0..7 as bf16x8 -> main kernel reads base+l*16 coalesced.
// ---------------------------------------------------------------------------
__global__ void rvq_prep(const float* __restrict__ cb,
                         unsigned short* __restrict__ cbi,
                         float* __restrict__ c2, unsigned* __restrict__ cnt) {
    int i = blockIdx.x * blockDim.x + threadIdx.x;   // 0..32767
    if (i < S * K) {   // c2 + cnt zero
        const float* row = cb + (size_t)i * D;
        float a0 = 0.f, a1 = 0.f, a2 = 0.f, a3 = 0.f;
#pragma unroll
        for (int d = 0; d < D; d += 4) {
            a0 = fmaf(row[d+0], row[d+0], a0);
            a1 = fmaf(row[d+1], row[d+1], a1);
            a2 = fmaf(row[d+2], row[d+2], a2);
            a3 = fmaf(row[d+3], row[d+3], a3);
        }
        c2[i] = (a0 + a1) + (a2 + a3);
        cnt[i] = 0u;
    }
    // interleave: i = s*4096 + tau*64 + l
    int s  = i >> 12;
    int tau = (i >> 6) & 63;
    int l  = i & 63;
    int m  = l & 15, qq = l >> 4;
    const float* row = cb + (size_t)(s * K + tau * 16 + m) * D;
    short8 h0h, h0l, h1h, h1l;
#pragma unroll
    for (int e = 0; e < 8; ++e) {
        float x = row[qq * 8 + e];
        unsigned short h = f2bf(x);
        h0h[e] = (short)h; h0l[e] = (short)f2bf(x - bf2f(h));
        float y = row[32 + qq * 8 + e];
        unsigned short g = f2bf(y);
        h1h[e] = (short)g; h1l[e] = (short)f2bf(y - bf2f(g));
    }
    unsigned short* rec = cbi + (size_t)(s * 64 + tau) * 2048 + l * 8;
    *(short8*)(rec +    0) = h0h;
    *(short8*)(rec +  512) = h1h;
    *(short8*)(rec + 1024) = h0l;
    *(short8*)(rec + 1536) = h1l;
}

// ---------------------------------------------------------------------------
// Main: one wave per block, 32 vectors (two 16-row MFMA sets sharing each
// B-fragment). No LDS, no barriers: B-frags stream from L2 (coalesced
// 16 B/lane), 2-bank prefetch pipeline. Top-2 + exact fp32 rescue (<DELTA).
// Residual/loss/zq pure fp32. Loss via plain per-wave stores (no atomics).
// R8 bug fixed: histogram used __shfl from exec-masked-off lanes (UB per
// ISA: ds_bpermute from inactive lane) -> now uses the convergently-
// computed bka/bkb winners directly (verified correct via outputs 0/1).
// ---------------------------------------------------------------------------
__global__ __launch_bounds__(64, 2)
void rvq_main(const float* __restrict__ z, const float* __restrict__ cbf,
              const unsigned short* __restrict__ cbi,
              const float* __restrict__ c2, float* __restrict__ zq,
              float* __restrict__ lossp, unsigned* __restrict__ cnt) {
    const int lane = threadIdx.x;
    const int m    = lane & 15;
    const int q    = lane >> 4;
    const int wid  = blockIdx.x;
    const int vbase = wid * 32;
    const int b    = vbase >> 12;
    const int ta   = (vbase & 4095) + m;        // set-a t
    const int tb   = ta + 16;                   // set-b t
    const size_t zrow = ((size_t)(b * 64)) << 12;

    float ra0[8], ra1[8], rb0[8], rb1[8];
#pragma unroll
    for (int i = 0; i < 8; ++i) {
        ra0[i] = z[zrow + ((size_t)(q*8+i)    << 12) + ta];
        ra1[i] = z[zrow + ((size_t)(32+q*8+i) << 12) + ta];
        rb0[i] = z[zrow + ((size_t)(q*8+i)    << 12) + tb];
        rb1[i] = z[zrow + ((size_t)(32+q*8+i) << 12) + tb];
    }

#define LOADTILE(B0v, B1v, B2v, B3v, CCv, tt) {                              \
        const unsigned short* p_ = recs + (size_t)(tt) * 2048 + lane * 8;    \
        B0v = *(const short8*)(p_);                                          \
        B1v = *(const short8*)(p_ + 512);                                    \
        B2v = *(const short8*)(p_ + 1024);                                   \
        B3v = *(const short8*)(p_ + 1536);                                   \
        CCv = c2s[(tt) * 16 + m]; }

#pragma unroll 1
    for (int s = 0; s < S; ++s) {
        // split residuals to bf16 hi/lo A-fragments
        short8 xa0h, xa0l, xa1h, xa1l, xb0h, xb0l, xb1h, xb1l;
#pragma unroll
        for (int i = 0; i < 8; ++i) {
            unsigned short h;
            h = f2bf(ra0[i]); xa0h[i] = (short)h; xa0l[i] = (short)f2bf(ra0[i] - bf2f(h));
            h = f2bf(ra1[i]); xa1h[i] = (short)h; xa1l[i] = (short)f2bf(ra1[i] - bf2f(h));
            h = f2bf(rb0[i]); xb0h[i] = (short)h; xb0l[i] = (short)f2bf(rb0[i] - bf2f(h));
            h = f2bf(rb1[i]); xb1h[i] = (short)h; xb1l[i] = (short)f2bf(rb1[i] - bf2f(h));
        }

        float b1a[4], b2a[4], b1b[4], b2b[4];
        int   k1a[4], k1b[4];
#pragma unroll
        for (int j = 0; j < 4; ++j) {
            b1a[j] = 3.4e38f; b2a[j] = 3.4e38f; k1a[j] = 0;
            b1b[j] = 3.4e38f; b2b[j] = 3.4e38f; k1b[j] = 0;
        }

        const unsigned short* recs = cbi + (size_t)s * 131072;
        const float*          c2s  = c2 + s * K;

        short8 A0, A1, A2, A3, C0, C1, C2, C3;   // two banks
        float  ca, cb2;
        LOADTILE(A0, A1, A2, A3, ca,  0);
        LOADTILE(C0, C1, C2, C3, cb2, 1);

#pragma unroll 1
        for (int tau = 0; tau < 64; tau += 2) {
            // ---- bank A: tile tau ----
            {
                short8 bh0 = A0, bh1 = A1, bl0 = A2, bl1 = A3;
                float  c2v = ca;
                if (tau + 2 < 64) LOADTILE(A0, A1, A2, A3, ca, tau + 2);
                float4v aa = {0.f,0.f,0.f,0.f}, ab = {0.f,0.f,0.f,0.f};
                aa = __builtin_amdgcn_mfma_f32_16x16x32_bf16(xa0h, bh0, aa, 0,0,0);
                aa = __builtin_amdgcn_mfma_f32_16x16x32_bf16(xa0l, bh0, aa, 0,0,0);
                aa = __builtin_amdgcn_mfma_f32_16x16x32_bf16(xa0h, bl0, aa, 0,0,0);
                aa = __builtin_amdgcn_mfma_f32_16x16x32_bf16(xa1h, bh1, aa, 0,0,0);
                aa = __builtin_amdgcn_mfma_f32_16x16x32_bf16(xa1l, bh1, aa, 0,0,0);
                aa = __builtin_amdgcn_mfma_f32_16x16x32_bf16(xa1h, bl1, aa, 0,0,0);
                ab = __builtin_amdgcn_mfma_f32_16x16x32_bf16(xb0h, bh0, ab, 0,0,0);
                ab = __builtin_amdgcn_mfma_f32_16x16x32_bf16(xb0l, bh0, ab, 0,0,0);
                ab = __builtin_amdgcn_mfma_f32_16x16x32_bf16(xb0h, bl0, ab, 0,0,0);
                ab = __builtin_amdgcn_mfma_f32_16x16x32_bf16(xb1h, bh1, ab, 0,0,0);
                ab = __builtin_amdgcn_mfma_f32_16x16x32_bf16(xb1l, bh1, ab, 0,0,0);
                ab = __builtin_amdgcn_mfma_f32_16x16x32_bf16(xb1h, bl1, ab, 0,0,0);
                int ncol = tau * 16 + m;
#pragma unroll
                for (int j = 0; j < 4; ++j) {
                    float sa = fmaf(-2.f, aa[j], c2v);
                    b2a[j] = fminf(b2a[j], fmaxf(sa, b1a[j]));
                    k1a[j] = (sa < b1a[j]) ? ncol : k1a[j];
                    b1a[j] = fminf(sa, b1a[j]);
                    float sb = fmaf(-2.f, ab[j], c2v);
                    b2b[j] = fminf(b2b[j], fmaxf(sb, b1b[j]));
                    k1b[j] = (sb < b1b[j]) ? ncol : k1b[j];
                    b1b[j] = fminf(sb, b1b[j]);
                }
            }
            // ---- bank B: tile tau+1 ----
            {
                short8 bh0 = C0, bh1 = C1, bl0 = C2, bl1 = C3;
                float  c2v = cb2;
                if (tau + 3 < 64) LOADTILE(C0, C1, C2, C3, cb2, tau + 3);
                float4v aa = {0.f,0.f,0.f,0.f}, ab = {0.f,0.f,0.f,0.f};
                aa = __builtin_amdgcn_mfma_f32_16x16x32_bf16(xa0h, bh0, aa, 0,0,0);
                aa = __builtin_amdgcn_mfma_f32_16x16x32_bf16(xa0l, bh0, aa, 0,0,0);
                aa = __builtin_amdgcn_mfma_f32_16x16x32_bf16(xa0h, bl0, aa, 0,0,0);
                aa = __builtin_amdgcn_mfma_f32_16x16x32_bf16(xa1h, bh1, aa, 0,0,0);
                aa = __builtin_amdgcn_mfma_f32_16x16x32_bf16(xa1l, bh1, aa, 0,0,0);
                aa = __builtin_amdgcn_mfma_f32_16x16x32_bf16(xa1h, bl1, aa, 0,0,0);
                ab = __builtin_amdgcn_mfma_f32_16x16x32_bf16(xb0h, bh0, ab, 0,0,0);
                ab = __builtin_amdgcn_mfma_f32_16x16x32_bf16(xb0l, bh0, ab, 0,0,0);
                ab = __builtin_amdgcn_mfma_f32_16x16x32_bf16(xb0h, bl0, ab, 0,0,0);
                ab = __builtin_amdgcn_mfma_f32_16x16x32_bf16(xb1h, bh1, ab, 0,0,0);
                ab = __builtin_amdgcn_mfma_f32_16x16x32_bf16(xb1l, bh1, ab, 0,0,0);
                ab = __builtin_amdgcn_mfma_f32_16x16x32_bf16(xb1h, bl1, ab, 0,0,0);
                int ncol = (tau + 1) * 16 + m;
#pragma unroll
                for (int j = 0; j < 4; ++j) {
                    float sa = fmaf(-2.f, aa[j], c2v);
                    b2a[j] = fminf(b2a[j], fmaxf(sa, b1a[j]));
                    k1a[j] = (sa < b1a[j]) ? ncol : k1a[j];
                    b1a[j] = fminf(sa, b1a[j]);
                    float sb = fmaf(-2.f, ab[j], c2v);
                    b2b[j] = fminf(b2b[j], fmaxf(sb, b1b[j]));
                    k1b[j] = (sb < b1b[j]) ? ncol : k1b[j];
                    b1b[j] = fminf(sb, b1b[j]);
                }
            }
        }

        // ---- reduce across the 16 col-lanes (k-tie: lowest k) ----
#pragma unroll
        for (int off = 1; off < 16; off <<= 1) {
#pragma unroll
            for (int j = 0; j < 4; ++j) {
                float o1 = __shfl_xor(b1a[j], off); int ok = __shfl_xor(k1a[j], off);
                float o2 = __shfl_xor(b2a[j], off);
                float n2 = fminf(fminf(b2a[j], o2), fmaxf(b1a[j], o1));
                bool tk = (o1 < b1a[j]) || (o1 == b1a[j] && ok < k1a[j]);
                k1a[j] = tk ? ok : k1a[j]; b1a[j] = fminf(b1a[j], o1); b2a[j] = n2;
                o1 = __shfl_xor(b1b[j], off); ok = __shfl_xor(k1b[j], off);
                o2 = __shfl_xor(b2b[j], off);
                n2 = fminf(fminf(b2b[j], o2), fmaxf(b1b[j], o1));
                tk = (o1 < b1b[j]) || (o1 == b1b[j] && ok < k1b[j]);
                k1b[j] = tk ? ok : k1b[j]; b1b[j] = fminf(b1b[j], o1); b2b[j] = n2;
            }
        }

        // ---- δ-rescue: exact fp32 rescan of ambiguous rows (rare) ----
        const float* cr0 = cbf + (size_t)s * 65536;
#define RESCUE(b1X, b2X, k1X, R0, R1)                                         \
        for (int j = 0; j < 4; ++j) {                                         \
            unsigned long long mask = __ballot(b2X[j] - b1X[j] < DELTA);      \
            while (mask) {                                                    \
                int lq = (int)(__builtin_ctzll(mask)) >> 4;                   \
                mask &= ~(0xFFFFULL << (lq * 16));                            \
                int mrow = lq * 4 + j;                                        \
                float bd = 3.4e38f; int bk = 0;                               \
                for (int cc = 0; cc < 16; ++cc) {                             \
                    int n = cc * 64 + lane;                                   \
                    const float* crow = cr0 + (size_t)n * 64;                 \
                    float dot = 0.f;                                          \
                    for (int p = 0; p < 4; ++p) {                             \
                        for (int i = 0; i < 8; ++i)                           \
                            dot = fmaf(__shfl(R0[i], mrow + 16*p), crow[p*8+i], dot); \
                        for (int i = 0; i < 8; ++i)                           \
                            dot = fmaf(__shfl(R1[i], mrow + 16*p), crow[32+p*8+i], dot); \
                    }                                                         \
                    float sc = c2s[n] - 2.f * dot;                            \
                    if (sc < bd) { bd = sc; bk = n; }                         \
                }                                                             \
                for (int off = 1; off < 64; off <<= 1) {                      \
                    float ob = __shfl_xor(bd, off); int ok = __shfl_xor(bk, off); \
                    bool tk = (ob < bd) || (ob == bd && ok < bk);             \
                    bk = tk ? ok : bk; bd = fminf(bd, ob);                    \
                }                                                             \
                if (q == lq) k1X[j] = bk;                                     \
            }                                                                 \
        }
        RESCUE(b1a, b2a, k1a, ra0, ra1)
        RESCUE(b1b, b2b, k1b, rb0, rb1)
#undef RESCUE

        // ---- transpose winners to per-lane rows (row = m), convergent ----
        int mm = m & 3, src = (m >> 2) * 16;
        int wa0 = __shfl(k1a[0], src), wa1 = __shfl(k1a[1], src);
        int wa2 = __shfl(k1a[2], src), wa3 = __shfl(k1a[3], src);
        int bka = (mm == 0) ? wa0 : (mm == 1) ? wa1 : (mm == 2) ? wa2 : wa3;
        int wb0 = __shfl(k1b[0], src), wb1 = __shfl(k1b[1], src);
        int wb2 = __shfl(k1b[2], src), wb3 = __shfl(k1b[3], src);
        int bkb = (mm == 0) ? wb0 : (mm == 1) ? wb1 : (mm == 2) ? wb2 : wb3;

        // ---- fp32 residual update ----
        const float* qa = cbf + (size_t)s * 65536 + (size_t)bka * 64;
        const float* qb = cbf + (size_t)s * 65536 + (size_t)bkb * 64;
#pragma unroll
        for (int i = 0; i < 8; ++i) {
            ra0[i] -= qa[q*8+i];  ra1[i] -= qa[32+q*8+i];
            rb0[i] -= qb[q*8+i];  rb1[i] -= qb[32+q*8+i];
        }

        // ---- loss: plain per-wave store (summed in finalize) ----
        float ls = 0.f;
#pragma unroll
        for (int i = 0; i < 8; ++i) {
            ls = fmaf(ra0[i], ra0[i], ls); ls = fmaf(ra1[i], ra1[i], ls);
            ls = fmaf(rb0[i], rb0[i], ls); ls = fmaf(rb1[i], rb1[i], ls);
        }
#pragma unroll
        for (int off = 1; off < 64; off <<= 1) ls += __shfl_xor(ls, off);
        if (lane == 0) lossp[s * NW + wid] = ls;

        // ---- histogram: bka/bkb are per-vector winners (dup across q) ----
        if (q == 0) {
            atomicAdd(&cnt[s * K + bka], 1u);   // vector vbase+m
            atomicAdd(&cnt[s * K + bkb], 1u);   // vector vbase+16+m
        }
    }
#undef LOADTILE

    // ---- epilogue: zq = z - r_final ----
#pragma unroll
    for (int i = 0; i < 8; ++i) {
        size_t a0 = zrow + ((size_t)(q*8+i)    << 12) + ta;
        size_t a1 = zrow + ((size_t)(32+q*8+i) << 12) + ta;
        zq[a0] = z[a0] - ra0[i];
        zq[a1] = z[a1] - ra1[i];
        size_t a2 = zrow + ((size_t)(q*8+i)    << 12) + tb;
        size_t a3 = zrow + ((size_t)(32+q*8+i) << 12) + tb;
        zq[a2] = z[a2] - rb0[i];
        zq[a3] = z[a3] - rb1[i];
    }
}

// ---------------------------------------------------------------------------
// Finalize: losses (mean of summed wave partials) + perplexities
// ---------------------------------------------------------------------------
__global__ void rvq_finalize(const float* __restrict__ lossp,
                             const unsigned* __restrict__ cnt,
                             float* __restrict__ out_loss,
                             float* __restrict__ out_perp) {
    const int s   = blockIdx.x;
    const int tid = threadIdx.x;
    float ent = 0.f, lsum = 0.f;
    for (int i = tid; i < K; i += 256) {
        float p = (float)cnt[s * K + i] * (1.0f / 65536.0f);
        ent += p * logf(p + EPSQ);
    }
    for (int i = tid; i < NW; i += 256) lsum += lossp[s * NW + i];
    __shared__ float redE[4], redL[4];
#pragma unroll
    for (int off = 32; off > 0; off >>= 1) {
        ent  += __shfl_down(ent, off);
        lsum += __shfl_down(lsum, off);
    }
    if ((tid & 63) == 0) { redE[tid >> 6] = ent; redL[tid >> 6] = lsum; }
    __syncthreads();
    if (tid == 0) {
        float te = redE[0] + redE[1] + redE[2] + redE[3];
        float tl = redL[0] + redL[1] + redL[2] + redL[3];
        out_perp[s] = expf(-te);
        out_loss[s] = tl * (1.0f / NELEM);
    }
}

// ---------------------------------------------------------------------------
extern "C" void kernel_launch(void* const* d_in, const int* in_sizes, int n_in,
                              void* d_out, int out_size, void* d_ws, size_t ws_size,
                              hipStream_t stream) {
    const float* z  = (const float*)d_in[0];
    const float* cb = (const float*)d_in[1];

    float* zq       = (float*)d_out;
    float* out_loss = zq + 4194304;
    float* out_perp = out_loss + 8;

    // ws: cbi 2 MB | c2 32 KB | cnt 32 KB | lossp 64 KB
    char* ws = (char*)d_ws;
    unsigned short* cbi = (unsigned short*)(ws);
    float*    c2    = (float*)(ws + 2097152);
    unsigned* cnt   = (unsigned*)(ws + 2129920);
    float*    lossp = (float*)(ws + 2162688);

    hipLaunchKernelGGL(rvq_prep,     dim3(128),  dim3(256), 0, stream, cb, cbi, c2, cnt);
    hipLaunchKernelGGL(rvq_main,     dim3(NW),   dim3(64),  0, stream, z, cb, cbi, c2, zq, lossp, cnt);
    hipLaunchKernelGGL(rvq_finalize, dim3(S),    dim3(256), 0, stream, lossp, cnt, out_loss, out_perp);
}